// Round 10
// baseline (73.958 us; speedup 1.0000x reference)
//
#include <hip/hip_runtime.h>

// ---------------------------------------------------------------------------
// AtomicLinear == x @ W^T + bias.  M=8192, N=2048, K=2048, fp32 in/out.
// R10: ZERO-LDS, barrier-free int8 GEMM.  Both A and W are pre-quantized
// (per-row symmetric, s=rowmax/127) into per-lane MFMA-fragment order; the
// GEMM streams A-frags (3 steps ahead, 4-slot rotation) and B-frags (1 tile
// ahead, reg double-buffer) straight from L2/L3 into registers with
// global_load_dwordx4.  No s_barrier, no LDS: 8 waves free-run and overlap
// each other's load windows with MFMA.  Sync = fully counted per-step
// vmcnt(N) ledger (steady 8,10,12,14,12,10,8,6; never 0 mid-loop).
// v_mfma_i32_16x16x64_i8; epilogue out = acc*sx[row]*sw[col] + bias[col].
// ---------------------------------------------------------------------------

typedef int            i32x4   __attribute__((ext_vector_type(4)));

static constexpr int Mdim = 8192, Ndim = 2048, Kdim = 2048;
static constexpr int KT = 16;                 // K-tiles of 128 i8
static constexpr int TBA = 32768;             // A frag bytes per (mt,kt)
static constexpr int TBB = 32768;             // B frag bytes per (nt,kt)

// ---------------------------------------------------------------------------
// Prepass A: one block per x-row; fused rowmax + quantize + fragment layout.
// Chunk g = ((((mt*16+kt)*2 + wr)*8 + mi)*2 + kk)*64 + fq*16 + fr holds
// x[mt*256 + wr*128 + mi*16 + fr][kt*128 + kk*64 + fq*16 .. +15] as i8.
// ---------------------------------------------------------------------------
__global__ void quantA(const float* __restrict__ src, signed char* __restrict__ dst,
                       float* __restrict__ scale) {
    const int row = blockIdx.x;
    const int j   = threadIdx.x;               // 0..255, elems k0 = j*8
    const int lane = j & 63, wid = j >> 6;
    const float* p = src + (size_t)row * 2048 + j * 8;
    float4 v0 = *(const float4*)p;
    float4 v1 = *(const float4*)(p + 4);
    float m = fmaxf(fmaxf(fmaxf(fabsf(v0.x), fabsf(v0.y)), fmaxf(fabsf(v0.z), fabsf(v0.w))),
                    fmaxf(fmaxf(fabsf(v1.x), fabsf(v1.y)), fmaxf(fabsf(v1.z), fabsf(v1.w))));
#pragma unroll
    for (int i = 1; i < 64; i <<= 1) m = fmaxf(m, __shfl_xor(m, i));
    __shared__ float wm[4];
    if (lane == 0) wm[wid] = m;
    __syncthreads();
    const float rm = fmaxf(fmaxf(wm[0], wm[1]), fmaxf(wm[2], wm[3]));
    const float qs = rm > 1e-30f ? 127.0f / rm : 0.0f;
    if (j == 0) scale[row] = rm > 1e-30f ? rm * (1.0f / 127.0f) : 0.0f;

    int q[8];
    q[0] = __float2int_rn(v0.x * qs); q[1] = __float2int_rn(v0.y * qs);
    q[2] = __float2int_rn(v0.z * qs); q[3] = __float2int_rn(v0.w * qs);
    q[4] = __float2int_rn(v1.x * qs); q[5] = __float2int_rn(v1.y * qs);
    q[6] = __float2int_rn(v1.z * qs); q[7] = __float2int_rn(v1.w * qs);
    uint2 pk;
    pk.x = (q[0] & 255) | ((q[1] & 255) << 8) | ((q[2] & 255) << 16) | ((unsigned)(q[3] & 255) << 24);
    pk.y = (q[4] & 255) | ((q[5] & 255) << 8) | ((q[6] & 255) << 16) | ((unsigned)(q[7] & 255) << 24);

    const int mt = row >> 8, r = row & 255;
    const int wr = r >> 7, mi = (r >> 4) & 7, fr = r & 15;
    const int kt = j >> 4, kk = (j >> 3) & 1, fq = (j >> 1) & 3, b8 = (j & 1) * 8;
    size_t g = ((((size_t)(mt * 16 + kt) * 2 + wr) * 8 + mi) * 2 + kk) * 64 + fq * 16 + fr;
    *(uint2*)(dst + g * 16 + b8) = pk;
}

// ---------------------------------------------------------------------------
// Prepass B (layout validated R9): chunk g = ((((nt*16+kt)*4+wc)*4+ni)*2+kk)*64
// + fq*16 + fr holds W[nt*256+wc*64+ni*16+fr][kt*128+kk*64+fq*16 .. +15].
// ---------------------------------------------------------------------------
__global__ void quantB(const float* __restrict__ src, signed char* __restrict__ dst,
                       float* __restrict__ scale) {
    const int row = blockIdx.x;
    const int j   = threadIdx.x;
    const int lane = j & 63, wid = j >> 6;
    const float* p = src + (size_t)row * 2048 + j * 8;
    float4 v0 = *(const float4*)p;
    float4 v1 = *(const float4*)(p + 4);
    float m = fmaxf(fmaxf(fmaxf(fabsf(v0.x), fabsf(v0.y)), fmaxf(fabsf(v0.z), fabsf(v0.w))),
                    fmaxf(fmaxf(fabsf(v1.x), fabsf(v1.y)), fmaxf(fabsf(v1.z), fabsf(v1.w))));
#pragma unroll
    for (int i = 1; i < 64; i <<= 1) m = fmaxf(m, __shfl_xor(m, i));
    __shared__ float wm[4];
    if (lane == 0) wm[wid] = m;
    __syncthreads();
    const float rm = fmaxf(fmaxf(wm[0], wm[1]), fmaxf(wm[2], wm[3]));
    const float qs = rm > 1e-30f ? 127.0f / rm : 0.0f;
    if (j == 0) scale[row] = rm > 1e-30f ? rm * (1.0f / 127.0f) : 0.0f;

    int q[8];
    q[0] = __float2int_rn(v0.x * qs); q[1] = __float2int_rn(v0.y * qs);
    q[2] = __float2int_rn(v0.z * qs); q[3] = __float2int_rn(v0.w * qs);
    q[4] = __float2int_rn(v1.x * qs); q[5] = __float2int_rn(v1.y * qs);
    q[6] = __float2int_rn(v1.z * qs); q[7] = __float2int_rn(v1.w * qs);
    uint2 pk;
    pk.x = (q[0] & 255) | ((q[1] & 255) << 8) | ((q[2] & 255) << 16) | ((unsigned)(q[3] & 255) << 24);
    pk.y = (q[4] & 255) | ((q[5] & 255) << 8) | ((q[6] & 255) << 16) | ((unsigned)(q[7] & 255) << 24);

    const int nt = row >> 8, wc = (row >> 6) & 3, ni = (row >> 4) & 3, fr = row & 15;
    const int kt = j >> 4, kk = (j >> 3) & 1, fq = (j >> 1) & 3, b8 = (j & 1) * 8;
    size_t g = ((((size_t)(nt * 16 + kt) * 4 + wc) * 4 + ni) * 2 + kk) * 64 + fq * 16 + fr;
    *(uint2*)(dst + g * 16 + b8) = pk;
}

#define LDX(dst, base, VOFF, IMM)                                               \
    asm volatile("global_load_dwordx4 %0, %1, %2 offset:%3"                     \
                 : "=v"(dst) : "v"(VOFF), "s"(base), "i"(IMM))

#define WAITA(N, sl)                                                            \
    asm volatile("s_waitcnt vmcnt(" #N ")" : "+v"(sl[0]), "+v"(sl[1]))

#define WAITG(N, sl, b)                                                         \
    asm volatile("s_waitcnt vmcnt(" #N ")"                                      \
                 : "+v"(sl[0]), "+v"(sl[1]),                                    \
                   "+v"(b[0][0]), "+v"(b[0][1]), "+v"(b[1][0]), "+v"(b[1][1]),  \
                   "+v"(b[2][0]), "+v"(b[2][1]), "+v"(b[3][0]), "+v"(b[3][1]))

template <int MI>
__device__ __forceinline__ void mfma8(i32x4 (&acc)[8][4], i32x4 (&s)[2],
                                      i32x4 (&bC)[4][2]) {
    __builtin_amdgcn_s_setprio(1);
#pragma unroll
    for (int kk = 0; kk < 2; ++kk)
#pragma unroll
        for (int ni = 0; ni < 4; ++ni)
            asm volatile("v_mfma_i32_16x16x64_i8 %0, %1, %2, %0"
                         : "+a"(acc[MI][ni]) : "v"(s[kk]), "v"(bC[ni][kk]));
    __builtin_amdgcn_s_setprio(0);
}

// One K-tile = 8 steps.  Steady: step s issues A(t)[s+3] (s<=4) or A(t+1)[s-5]
// (s>=5) and 2 B(t+1) frags (s<=3); counted vmcnt per the audited ledger.
// Slot rotation: A[mi] lives in sA[mi&3]; every overwrite is exactly one step
// after its last read.  TAIL: tile 15, no B / no next-A, ledger shrinks to 0.
template <bool TAIL>
__device__ __forceinline__ void tile10(
    i32x4 (&acc)[8][4], i32x4 (&bC)[4][2], i32x4 (&bN)[4][2], i32x4 (&sA)[4][2],
    const char* aC, const char* aN, const char* bNp,
    unsigned vA0, unsigned vA1, unsigned vA2, unsigned vA3,
    unsigned vB0, unsigned vB1) {
    // s0: load A[3]->slot3; B#0,#1; need A[0]+all bC
    LDX(sA[3][0], aC, vA1, 2048); LDX(sA[3][1], aC, vA1, 3072);
    if constexpr (!TAIL) { LDX(bN[0][0], bNp, vB0, 0); LDX(bN[0][1], bNp, vB0, 1024); }
    if constexpr (!TAIL) { WAITG(8, sA[0], bC); } else { WAITG(6, sA[0], bC); }
    mfma8<0>(acc, sA[0], bC);
    // s1: load A[4]->slot0; B#2,#3; need A[1]
    LDX(sA[0][0], aC, vA2, 0); LDX(sA[0][1], aC, vA2, 1024);
    if constexpr (!TAIL) { LDX(bN[1][0], bNp, vB0, 2048); LDX(bN[1][1], bNp, vB0, 3072); }
    if constexpr (!TAIL) { WAITA(10, sA[1]); } else { WAITA(6, sA[1]); }
    mfma8<1>(acc, sA[1], bC);
    // s2: load A[5]->slot1; B#4,#5; need A[2]
    LDX(sA[1][0], aC, vA2, 2048); LDX(sA[1][1], aC, vA2, 3072);
    if constexpr (!TAIL) { LDX(bN[2][0], bNp, vB1, 0); LDX(bN[2][1], bNp, vB1, 1024); }
    if constexpr (!TAIL) { WAITA(12, sA[2]); } else { WAITA(6, sA[2]); }
    mfma8<2>(acc, sA[2], bC);
    // s3: load A[6]->slot2; B#6,#7; need A[3]
    LDX(sA[2][0], aC, vA3, 0); LDX(sA[2][1], aC, vA3, 1024);
    if constexpr (!TAIL) { LDX(bN[3][0], bNp, vB1, 2048); LDX(bN[3][1], bNp, vB1, 3072); }
    if constexpr (!TAIL) { WAITA(14, sA[3]); } else { WAITA(6, sA[3]); }
    mfma8<3>(acc, sA[3], bC);
    // s4: load A[7]->slot3; need A[4]
    LDX(sA[3][0], aC, vA3, 2048); LDX(sA[3][1], aC, vA3, 3072);
    if constexpr (!TAIL) { WAITA(12, sA[0]); } else { WAITA(6, sA[0]); }
    mfma8<4>(acc, sA[0], bC);
    // s5: load An[0]->slot0; need A[5]
    if constexpr (!TAIL) { LDX(sA[0][0], aN, vA0, 0); LDX(sA[0][1], aN, vA0, 1024); }
    if constexpr (!TAIL) { WAITA(10, sA[1]); } else { WAITA(4, sA[1]); }
    mfma8<5>(acc, sA[1], bC);
    // s6: load An[1]->slot1; need A[6]
    if constexpr (!TAIL) { LDX(sA[1][0], aN, vA0, 2048); LDX(sA[1][1], aN, vA0, 3072); }
    if constexpr (!TAIL) { WAITA(8, sA[2]); } else { WAITA(2, sA[2]); }
    mfma8<6>(acc, sA[2], bC);
    // s7: load An[2]->slot2; need A[7]
    if constexpr (!TAIL) { LDX(sA[2][0], aN, vA1, 0); LDX(sA[2][1], aN, vA1, 1024); }
    if constexpr (!TAIL) { WAITA(6, sA[3]); } else { WAITA(0, sA[3]); }
    mfma8<7>(acc, sA[3], bC);
}

// 256x256 block tile, 512 threads (8 waves 2M x 4N), wave tile 128x64.
// NO LDS, NO barriers.
__global__ __launch_bounds__(512, 2) void gemm10(
    const signed char* __restrict__ xa, const signed char* __restrict__ wbf,
    const float* __restrict__ sx, const float* __restrict__ sw,
    const float* __restrict__ bias, float* __restrict__ out) {
    const int tid  = threadIdx.x;
    const int lane = tid & 63, wid = tid >> 6;
    const int wr   = wid >> 2;                   // 0..1  (A row half)
    const int wc   = wid & 3;                    // 0..3  (B col quarter)
    const int fr   = lane & 15, fq = lane >> 4;

    const int bid = blockIdx.x;                  // 256 blocks = 1/CU
    const int nt  = bid & 7;                     // XCD-pinned B panel (T1)
    const int mt  = bid >> 3;                    // 0..31

    const char* aT = (const char*)xa + (size_t)mt * KT * TBA;
    const char* bP = (const char*)wbf + (size_t)nt * KT * TBB;

    const unsigned vA0 = (unsigned)(wr * 16384 + lane * 16);
    const unsigned vA1 = vA0 + 4096u, vA2 = vA0 + 8192u, vA3 = vA0 + 12288u;
    const unsigned vB0 = (unsigned)(wc * 8192 + lane * 16);
    const unsigned vB1 = vB0 + 4096u;

    i32x4 acc[8][4];
#pragma unroll
    for (int i = 0; i < 8; ++i)
#pragma unroll
        for (int j = 0; j < 4; ++j)
            acc[i][j] = i32x4{0, 0, 0, 0};
    i32x4 bfU[4][2], bfV[4][2], sA[4][2];

    // Prologue: B(0)#0..7 then A(0)[0..2] (order matters for the ledger).
    LDX(bfU[0][0], bP, vB0, 0);    LDX(bfU[0][1], bP, vB0, 1024);
    LDX(bfU[1][0], bP, vB0, 2048); LDX(bfU[1][1], bP, vB0, 3072);
    LDX(bfU[2][0], bP, vB1, 0);    LDX(bfU[2][1], bP, vB1, 1024);
    LDX(bfU[3][0], bP, vB1, 2048); LDX(bfU[3][1], bP, vB1, 3072);
    LDX(sA[0][0], aT, vA0, 0);     LDX(sA[0][1], aT, vA0, 1024);
    LDX(sA[1][0], aT, vA0, 2048);  LDX(sA[1][1], aT, vA0, 3072);
    LDX(sA[2][0], aT, vA1, 0);     LDX(sA[2][1], aT, vA1, 1024);

    // 15 steady tiles (t=0..14), bC parity swaps; then tail t=15.
#pragma unroll 1
    for (int it = 0; it < 7; ++it) {
        const int t = 2 * it;
        tile10<false>(acc, bfU, bfV, sA,
                      aT + (size_t)t * TBA, aT + (size_t)(t + 1) * TBA,
                      bP + (size_t)(t + 1) * TBB, vA0, vA1, vA2, vA3, vB0, vB1);
        tile10<false>(acc, bfV, bfU, sA,
                      aT + (size_t)(t + 1) * TBA, aT + (size_t)(t + 2) * TBA,
                      bP + (size_t)(t + 2) * TBB, vA0, vA1, vA2, vA3, vB0, vB1);
    }
    tile10<false>(acc, bfU, bfV, sA,
                  aT + (size_t)14 * TBA, aT + (size_t)15 * TBA,
                  bP + (size_t)15 * TBB, vA0, vA1, vA2, vA3, vB0, vB1);
    tile10<true>(acc, bfV, bfU, sA,
                 aT + (size_t)15 * TBA, aT, bP, vA0, vA1, vA2, vA3, vB0, vB1);

    // Epilogue: row = mt*256 + wr*128 + mi*16 + fq*4 + rr;
    //           col = nt*256 + wc*64 + ni*16 + fr.
    const int gr0 = mt * 256 + wr * 128 + fq * 4;
    const int gc0 = nt * 256 + wc * 64;
#pragma unroll
    for (int ni = 0; ni < 4; ++ni) {
        const int cn = gc0 + ni * 16 + fr;
        const float tv = sw[cn];
        const float bv = bias[cn];
#pragma unroll
        for (int mi = 0; mi < 8; ++mi) {
            const int rm = gr0 + mi * 16;
            const float4 sv = *(const float4*)&sx[rm];
            out[(size_t)(rm + 0) * Ndim + cn] = (float)acc[mi][ni][0] * sv.x * tv + bv;
            out[(size_t)(rm + 1) * Ndim + cn] = (float)acc[mi][ni][1] * sv.y * tv + bv;
            out[(size_t)(rm + 2) * Ndim + cn] = (float)acc[mi][ni][2] * sv.z * tv + bv;
            out[(size_t)(rm + 3) * Ndim + cn] = (float)acc[mi][ni][3] * sv.w * tv + bv;
        }
    }
}

// Correct-but-slow fp32 fallback if workspace is too small.
__global__ void fallback_gemm(const float* __restrict__ x, const float* __restrict__ w,
                              const float* __restrict__ bias, float* __restrict__ out) {
    __shared__ float As[64][17];
    __shared__ float Bs[64][17];
    int tx = threadIdx.x & 15, ty = threadIdx.x >> 4;
    int m0 = blockIdx.y * 64, n0 = blockIdx.x * 64;
    float acc[4][4] = {};
    for (int k0 = 0; k0 < Kdim; k0 += 16) {
#pragma unroll
        for (int i = 0; i < 4; ++i) {
            int idx = threadIdx.x + i * 256;
            int rr = idx >> 4, cc = idx & 15;
            As[rr][cc] = x[(size_t)(m0 + rr) * Kdim + k0 + cc];
            Bs[rr][cc] = w[(size_t)(n0 + rr) * Kdim + k0 + cc];
        }
        __syncthreads();
#pragma unroll
        for (int kk = 0; kk < 16; ++kk) {
            float a[4], b[4];
#pragma unroll
            for (int i = 0; i < 4; ++i) a[i] = As[ty * 4 + i][kk];
#pragma unroll
            for (int j = 0; j < 4; ++j) b[j] = Bs[tx * 4 + j][kk];
#pragma unroll
            for (int i = 0; i < 4; ++i)
#pragma unroll
                for (int j = 0; j < 4; ++j) acc[i][j] += a[i] * b[j];
        }
        __syncthreads();
    }
#pragma unroll
    for (int i = 0; i < 4; ++i)
#pragma unroll
        for (int j = 0; j < 4; ++j) {
            int gm = m0 + ty * 4 + i, gn = n0 + tx * 4 + j;
            out[(size_t)gm * Ndim + gn] = acc[i][j] + bias[gn];
        }
}

extern "C" void kernel_launch(void* const* d_in, const int* in_sizes, int n_in,
                              void* d_out, int out_size, void* d_ws, size_t ws_size,
                              hipStream_t stream) {
    const float* x    = (const float*)d_in[0];
    const float* w    = (const float*)d_in[1];
    const float* bias = (const float*)d_in[2];
    float* out        = (float*)d_out;

    const size_t needA = (size_t)Mdim * Kdim;            // 16.8 MB i8 image
    const size_t needB = (size_t)Ndim * Kdim;            //  4.2 MB i8 image
    const size_t needS = (Mdim + Ndim) * sizeof(float);  // scales

    if (ws_size >= needA + needB + needS) {
        signed char* xa  = (signed char*)d_ws;
        signed char* wbf = xa + needA;
        float* sx        = (float*)(wbf + needB);
        float* sw        = sx + Mdim;
        quantA<<<Mdim, 256, 0, stream>>>(x, xa, sx);
        quantB<<<Ndim, 256, 0, stream>>>(w, wbf, sw);
        gemm10<<<(Mdim / 256) * (Ndim / 256), 512, 0, stream>>>(
            xa, wbf, sx, sw, bias, out);
    } else {
        dim3 grid(Ndim / 64, Mdim / 64);
        fallback_gemm<<<grid, 256, 0, stream>>>(x, w, bias, out);
    }
}